// Round 1
// baseline (2202.877 us; speedup 1.0000x reference)
//
#include <hip/hip_runtime.h>
#include <hip/hip_bf16.h>
#include <stdint.h>

typedef unsigned short u16;
typedef unsigned int u32;
typedef __attribute__((ext_vector_type(4))) float f32x4;
typedef __attribute__((ext_vector_type(8))) short s16x8;

#define B_   4096
#define N_   64
#define DX_  512
#define DD_  64
#define H_   8
#define DA_  64
#define HD_  512      // H*DA
#define KKV  640      // DX + 2*DD
#define MAXDEG 1000
#define MAXDIST 8

__device__ __forceinline__ float bf2f(u16 u) {
    union { u32 i; float f; } v; v.i = ((u32)u) << 16; return v.f;
}
__device__ __forceinline__ u16 f2bf(float f) {
    union { float f; u32 i; } v; v.f = f;
    u32 u = v.i;
    u32 r = (u + 0x7FFFu + ((u >> 16) & 1u)) >> 16;
    return (u16)r;
}

// ---------------------------------------------------------------- sentinel
__global__ void k_sentinel(float* out, int n) {
    int i = blockIdx.x * 256 + threadIdx.x;
    for (; i < n; i += gridDim.x * 256) out[i] = 31337.0f;
}

// ---------------------------------------------------------------- mask dtype detect
__global__ void k_zero_flag(int* flag) {
    if (threadIdx.x == 0) *flag = 0;
}
// If mask uploaded as 1-byte bool: bytes at i%4!=0 are ~50% nonzero.
// If uploaded as int32 (values 0/1): those bytes are always 0.
__global__ void k_detect_mask(const unsigned char* m, int* flag) {
    int i = blockIdx.x * 256 + threadIdx.x;
    int bad = 0;
    for (int j = i; j < B_ * N_; j += 64 * 256) {
        if ((j & 3) != 0 && m[j]) bad = 1;
    }
    unsigned long long anyb = __ballot(bad);
    if (anyb != 0ull && (threadIdx.x & 63) == 0) atomicOr(flag, 1);
}

// ---------------------------------------------------------------- table renorm (inf-norm<=1) + bf16
__global__ void k_prep_tables(const float* __restrict__ deg_k, const float* __restrict__ deg_v,
                              const float* __restrict__ dist_k, const float* __restrict__ dist_v,
                              u16* __restrict__ o_deg_k, u16* __restrict__ o_deg_v,
                              u16* __restrict__ o_dist_k, u16* __restrict__ o_dist_v) {
    int b = blockIdx.x, lane = threadIdx.x;  // 64 threads
    const float* src; u16* dst; int row;
    if (b < 1001)      { src = deg_k;  dst = o_deg_k;  row = b; }
    else if (b < 2002) { src = deg_v;  dst = o_deg_v;  row = b - 1001; }
    else if (b < 2011) { src = dist_k; dst = o_dist_k; row = b - 2002; }
    else               { src = dist_v; dst = o_dist_v; row = b - 2011; }
    float v = src[row * 64 + lane];
    float m = fabsf(v);
    for (int o = 32; o; o >>= 1) m = fmaxf(m, __shfl_xor(m, o, 64));
    float scale = fminf(1.0f, 1.0f / fmaxf(m, 1e-12f));
    dst[row * 64 + lane] = f2bf(v * scale);
}

// ---------------------------------------------------------------- f32 -> bf16 convert
__global__ void k_cvt_bf16(const float* __restrict__ src, u16* __restrict__ dst, int n4) {
    int i = blockIdx.x * 256 + threadIdx.x;
    if (i < n4) {
        float4 v = ((const float4*)src)[i];
        ushort4 o;
        o.x = f2bf(v.x); o.y = f2bf(v.y); o.z = f2bf(v.z); o.w = f2bf(v.w);
        ((ushort4*)dst)[i] = o;
    }
}

// ---------------------------------------------------------------- GEMM: out[M,N] = A[M,K] * Bt[N,K]^T
// A_MODE 0: A is bf16 matrix Abf (M x K)
// A_MODE 1: A cols 0..511 from xj f32 (converted in staging), cols 512..575 deg table
//           gather (bf16, prenormalized), cols 576..639 dist table gather.
// Tile 128x128, BK=64, 4 waves (2x2 of 64x64), LDS double-buffered, XOR swizzle.
template<int A_MODE, int OUT_BF16>
__launch_bounds__(256)
__global__ void k_gemm(const float* __restrict__ Axj,
                       const u16* __restrict__ Abf,
                       const int* __restrict__ degs,
                       const int* __restrict__ dists,
                       const u16* __restrict__ deg_tab,
                       const u16* __restrict__ dist_tab,
                       const u16* __restrict__ Bt,
                       float* __restrict__ out_f32,
                       u16* __restrict__ out_bf16,
                       int M, int Nn, int K) {
    __shared__ __align__(16) char smem[65536];  // 2 bufs * (A 16KB + B 16KB)
    const int tid  = threadIdx.x;
    const int lane = tid & 63;
    const int wid  = tid >> 6;
    const int wr = wid >> 1, wc = wid & 1;
    const int nTilesN = Nn >> 7;
    const int mt = blockIdx.x / nTilesN;
    const int nt = blockIdx.x % nTilesN;
    const int m0 = mt << 7, n0 = nt << 7;
    const int NS = K >> 6;

    const int r_base = tid >> 3;        // 0..31 (row within 32-row chunk)
    const int c8 = (tid & 7) * 8;       // col (elements) within BK=64

    float4 af0[4], af1[4];
    int4 ai[4], bi[4];

    auto load_tile = [&](int k0) {
#pragma unroll
        for (int c = 0; c < 4; c++) {
            int rl = c * 32 + r_base;
            int rg = m0 + rl;
            if (A_MODE == 0) {
                ai[c] = *(const int4*)(Abf + rg * K + k0 + c8);
            } else {
                if (k0 < DX_) {
                    const float* s = Axj + rg * DX_ + k0 + c8;
                    af0[c] = *(const float4*)s;
                    af1[c] = *(const float4*)(s + 4);
                } else if (k0 < DX_ + DD_) {
                    int idx = degs[rg]; idx = idx > MAXDEG ? MAXDEG : idx;
                    ai[c] = *(const int4*)(deg_tab + idx * 64 + (k0 - DX_) + c8);
                } else {
                    int idx = dists[rg]; idx = idx > MAXDIST ? MAXDIST : idx;
                    ai[c] = *(const int4*)(dist_tab + idx * 64 + (k0 - DX_ - DD_) + c8);
                }
            }
            int rb = n0 + rl;
            bi[c] = *(const int4*)(Bt + rb * K + k0 + c8);
        }
    };

    auto store_tile = [&](int buf, int k0) {
        char* As = smem + buf * 32768;
        char* Bs = smem + buf * 32768 + 16384;
#pragma unroll
        for (int c = 0; c < 4; c++) {
            int rl = c * 32 + r_base;
            int off = (rl * 128 + c8 * 2) ^ ((rl & 7) << 4);
            int4 av;
            if (A_MODE == 1 && k0 < DX_) {
                u32 p0 = (u32)f2bf(af0[c].x) | ((u32)f2bf(af0[c].y) << 16);
                u32 p1 = (u32)f2bf(af0[c].z) | ((u32)f2bf(af0[c].w) << 16);
                u32 p2 = (u32)f2bf(af1[c].x) | ((u32)f2bf(af1[c].y) << 16);
                u32 p3 = (u32)f2bf(af1[c].z) | ((u32)f2bf(af1[c].w) << 16);
                av.x = (int)p0; av.y = (int)p1; av.z = (int)p2; av.w = (int)p3;
            } else {
                av = ai[c];
            }
            *(int4*)(As + off) = av;
            *(int4*)(Bs + off) = bi[c];
        }
    };

    f32x4 acc[4][4];
    f32x4 zero; zero[0] = 0.f; zero[1] = 0.f; zero[2] = 0.f; zero[3] = 0.f;
#pragma unroll
    for (int i = 0; i < 4; i++)
#pragma unroll
        for (int j = 0; j < 4; j++) acc[i][j] = zero;

    const int l16 = lane & 15, lh = lane >> 4;

    load_tile(0);
    store_tile(0, 0);
    for (int s = 0; s < NS; s++) {
        __syncthreads();
        int k0n = (s + 1) << 6;
        if (s + 1 < NS) load_tile(k0n);
        {   // compute on buf s&1
            const char* As = smem + (s & 1) * 32768;
            const char* Bs = As + 16384;
#pragma unroll
            for (int kk = 0; kk < 2; kk++) {
                s16x8 a[4], b[4];
#pragma unroll
                for (int i = 0; i < 4; i++) {
                    int ra = wr * 64 + i * 16 + l16;
                    int offa = (ra * 128 + kk * 64 + lh * 16) ^ ((ra & 7) << 4);
                    a[i] = *(const s16x8*)(As + offa);
                    int rb = wc * 64 + i * 16 + l16;
                    int offb = (rb * 128 + kk * 64 + lh * 16) ^ ((rb & 7) << 4);
                    b[i] = *(const s16x8*)(Bs + offb);
                }
#pragma unroll
                for (int i = 0; i < 4; i++)
#pragma unroll
                    for (int j = 0; j < 4; j++)
                        acc[i][j] = __builtin_amdgcn_mfma_f32_16x16x32_bf16(a[i], b[j], acc[i][j], 0, 0, 0);
            }
        }
        if (s + 1 < NS) store_tile((s + 1) & 1, k0n);
    }

    // epilogue: D row = (lane>>4)*4 + r, col = lane&15 (verified layout)
#pragma unroll
    for (int i = 0; i < 4; i++) {
#pragma unroll
        for (int j = 0; j < 4; j++) {
#pragma unroll
            for (int r = 0; r < 4; r++) {
                int rg = m0 + wr * 64 + i * 16 + lh * 4 + r;
                int cg = n0 + wc * 64 + j * 16 + l16;
                float val = acc[i][j][r];
                if (OUT_BF16) out_bf16[rg * Nn + cg] = f2bf(val);
                else          out_f32[rg * Nn + cg] = val;
            }
        }
    }
}

// ---------------------------------------------------------------- attention (one block per b)
// scores from global k (each thread streams one row-slice), V staged to LDS for PV.
__launch_bounds__(256)
__global__ void k_attn(const float* __restrict__ q,    // (B,512) f32
                       const u16* __restrict__ k,      // (B*64,512) bf16
                       const u16* __restrict__ v,      // (B*64,512) bf16
                       const void* __restrict__ maskp,
                       const int* __restrict__ flag,
                       float* __restrict__ alpha_out,  // (B,H,N) f32
                       u16* __restrict__ attn_out) {   // (B,512) bf16
    __shared__ __align__(16) u16 v_sh[64 * 512];       // 64KB
    const int b = blockIdx.x;
    const int tid = threadIdx.x;

    // stage V[b] -> LDS (coalesced)
    {
        const int4* src = (const int4*)(v + (size_t)b * 64 * 512);
        int4* dst = (int4*)v_sh;
        for (int it = 0; it < 16; it++) dst[it * 256 + tid] = src[it * 256 + tid];
    }

    const int h = tid >> 5, i = tid & 31;
    const float* qh = q + b * 512 + h * 64;
    const int mflag = *flag;

    float s0, s1;
#pragma unroll
    for (int p = 0; p < 2; p++) {
        int n = i + p * 32;
        bool mval;
        if (mflag) mval = ((const unsigned char*)maskp)[b * 64 + n] != 0;
        else       mval = ((const int*)maskp)[b * 64 + n] != 0;
        if (n == 0) mval = true;
        const u16* kr = k + ((size_t)(b * 64 + n)) * 512 + h * 64;
        float acc = 0.f;
#pragma unroll
        for (int c = 0; c < 8; c++) {
            int4 kv = ((const int4*)kr)[c];
            float4 q0 = ((const float4*)qh)[c * 2];
            float4 q1 = ((const float4*)qh)[c * 2 + 1];
            acc += q0.x * bf2f((u16)((u32)kv.x & 0xffff));
            acc += q0.y * bf2f((u16)((u32)kv.x >> 16));
            acc += q0.z * bf2f((u16)((u32)kv.y & 0xffff));
            acc += q0.w * bf2f((u16)((u32)kv.y >> 16));
            acc += q1.x * bf2f((u16)((u32)kv.z & 0xffff));
            acc += q1.y * bf2f((u16)((u32)kv.z >> 16));
            acc += q1.z * bf2f((u16)((u32)kv.w & 0xffff));
            acc += q1.w * bf2f((u16)((u32)kv.w >> 16));
        }
        float sv = mval ? acc * 0.125f : -10000000.0f;
        if (p == 0) s0 = sv; else s1 = sv;
    }

    // softmax over 64 entries held 2-per-lane across the 32-lane group
    float m = fmaxf(s0, s1);
    for (int o = 16; o; o >>= 1) m = fmaxf(m, __shfl_xor(m, o, 32));
    float e0 = expf(s0 - m), e1 = expf(s1 - m);
    float sum = e0 + e1;
    for (int o = 16; o; o >>= 1) sum += __shfl_xor(sum, o, 32);
    float inv = 1.0f / sum;
    float a0 = e0 * inv, a1 = e1 * inv;
    alpha_out[(size_t)b * 512 + h * 64 + i]      = a0;
    alpha_out[(size_t)b * 512 + h * 64 + i + 32] = a1;

    __syncthreads();  // V staged & visible

    // PV: thread handles d0 = 2i, 2i+1
    const int d0 = 2 * i;
    float r0 = 0.f, r1 = 0.f;
    for (int n = 0; n < 64; n++) {
        float an = (n < 32) ? __shfl(a0, n, 32) : __shfl(a1, n - 32, 32);
        u32 pv = *(const u32*)(v_sh + n * 512 + h * 64 + d0);
        r0 += an * bf2f((u16)(pv & 0xffff));
        r1 += an * bf2f((u16)(pv >> 16));
    }
    u32 packed = (u32)f2bf(r0) | ((u32)f2bf(r1) << 16);
    *(u32*)(attn_out + (size_t)b * 512 + h * 64 + d0) = packed;
}

// ---------------------------------------------------------------- residual + LayerNorm
__launch_bounds__(64)
__global__ void k_ln(const float* __restrict__ xi, const float* __restrict__ attnO,
                     const float* __restrict__ gamma, const float* __restrict__ beta,
                     float* __restrict__ y) {
    const int b = blockIdx.x, t = threadIdx.x;
    const float4* xi4 = (const float4*)(xi + (size_t)b * 512);
    const float4* ao4 = (const float4*)(attnO + (size_t)b * 512);
    float vals[8];
    float s = 0.f;
#pragma unroll
    for (int c = 0; c < 2; c++) {
        float4 a = xi4[t * 2 + c], o = ao4[t * 2 + c];
        vals[c * 4 + 0] = a.x + o.x; vals[c * 4 + 1] = a.y + o.y;
        vals[c * 4 + 2] = a.z + o.z; vals[c * 4 + 3] = a.w + o.w;
        s += vals[c * 4 + 0] + vals[c * 4 + 1] + vals[c * 4 + 2] + vals[c * 4 + 3];
    }
    for (int o = 32; o; o >>= 1) s += __shfl_xor(s, o, 64);
    float mu = s * (1.0f / 512.0f);
    float vsum = 0.f;
#pragma unroll
    for (int j = 0; j < 8; j++) { float d = vals[j] - mu; vsum += d * d; }
    for (int o = 32; o; o >>= 1) vsum += __shfl_xor(vsum, o, 64);
    float rs = rsqrtf(vsum * (1.0f / 512.0f) + 1e-5f);
#pragma unroll
    for (int c = 0; c < 2; c++) {
        float4 g = ((const float4*)gamma)[t * 2 + c];
        float4 bb = ((const float4*)beta)[t * 2 + c];
        float4 o;
        o.x = (vals[c * 4 + 0] - mu) * rs * g.x + bb.x;
        o.y = (vals[c * 4 + 1] - mu) * rs * g.y + bb.y;
        o.z = (vals[c * 4 + 2] - mu) * rs * g.z + bb.z;
        o.w = (vals[c * 4 + 3] - mu) * rs * g.w + bb.w;
        ((float4*)(y + (size_t)b * 512))[t * 2 + c] = o;
    }
}

// ---------------------------------------------------------------- launch
extern "C" void kernel_launch(void* const* d_in, const int* in_sizes, int n_in,
                              void* d_out, int out_size, void* d_ws, size_t ws_size,
                              hipStream_t stream) {
    const float* xi     = (const float*)d_in[0];
    const float* xj     = (const float*)d_in[1];
    const int*   degs   = (const int*)d_in[2];
    const int*   dists  = (const int*)d_in[3];
    const void*  mask   = d_in[4];
    const float* W_q    = (const float*)d_in[5];
    const float* W_k    = (const float*)d_in[6];
    const float* W_v    = (const float*)d_in[7];
    const float* W_o    = (const float*)d_in[8];
    const float* deg_k  = (const float*)d_in[9];
    const float* deg_v  = (const float*)d_in[10];
    const float* dist_k = (const float*)d_in[11];
    const float* dist_v = (const float*)d_in[12];
    const float* ln_g   = (const float*)d_in[13];
    const float* ln_b   = (const float*)d_in[14];

    char* ws = (char*)d_ws;
    size_t off = 0;
    auto alloc = [&](size_t bytes) -> void* {
        void* p = ws + off; off += (bytes + 255) & ~(size_t)255; return p;
    };
    float* q       = (float*)alloc((size_t)B_ * HD_ * 4);
    float* attnO   = (float*)alloc((size_t)B_ * DX_ * 4);
    u16*   xi_bf   = (u16*)alloc((size_t)B_ * DX_ * 2);
    u16*   attn_bf = (u16*)alloc((size_t)B_ * HD_ * 2);
    u16*   Wq_bf   = (u16*)alloc((size_t)HD_ * DX_ * 2);
    u16*   Wk_bf   = (u16*)alloc((size_t)HD_ * KKV * 2);
    u16*   Wv_bf   = (u16*)alloc((size_t)HD_ * KKV * 2);
    u16*   Wo_bf   = (u16*)alloc((size_t)DX_ * HD_ * 2);
    u16*   dkt     = (u16*)alloc(1001ull * 64 * 2);
    u16*   dvt     = (u16*)alloc(1001ull * 64 * 2);
    u16*   skt     = (u16*)alloc(9ull * 64 * 2);
    u16*   svt     = (u16*)alloc(9ull * 64 * 2);
    int*   flag    = (int*)alloc(256);
    u16*   kbuf    = (u16*)alloc((size_t)B_ * N_ * HD_ * 2);
    u16*   vbuf    = (u16*)alloc((size_t)B_ * N_ * HD_ * 2);

    float* y     = (float*)d_out;
    float* alpha = (float*)d_out + (size_t)B_ * DX_;

    if (ws_size < off) {  // unambiguous sentinel: ws too small
        k_sentinel<<<1024, 256, 0, stream>>>((float*)d_out, out_size);
        return;
    }

    k_zero_flag<<<1, 64, 0, stream>>>(flag);
    k_detect_mask<<<64, 256, 0, stream>>>((const unsigned char*)mask, flag);
    k_prep_tables<<<2020, 64, 0, stream>>>(deg_k, deg_v, dist_k, dist_v, dkt, dvt, skt, svt);
    k_cvt_bf16<<<(B_ * DX_ / 4 + 255) / 256, 256, 0, stream>>>(xi, xi_bf, B_ * DX_ / 4);
    k_cvt_bf16<<<(HD_ * DX_ / 4 + 255) / 256, 256, 0, stream>>>(W_q, Wq_bf, HD_ * DX_ / 4);
    k_cvt_bf16<<<(HD_ * KKV / 4 + 255) / 256, 256, 0, stream>>>(W_k, Wk_bf, HD_ * KKV / 4);
    k_cvt_bf16<<<(HD_ * KKV / 4 + 255) / 256, 256, 0, stream>>>(W_v, Wv_bf, HD_ * KKV / 4);
    k_cvt_bf16<<<(DX_ * HD_ / 4 + 255) / 256, 256, 0, stream>>>(W_o, Wo_bf, DX_ * HD_ / 4);

    // Q = xi @ W_q^T   (M=4096, N=512, K=512), out f32
    k_gemm<0, 0><<<(B_ / 128) * (HD_ / 128), 256, 0, stream>>>(
        nullptr, xi_bf, nullptr, nullptr, nullptr, nullptr, Wq_bf, q, nullptr, B_, HD_, DX_);
    // K = [xj|deg|dist] @ W_k^T  (M=262144, N=512, K=640), out bf16
    k_gemm<1, 1><<<(B_ * N_ / 128) * (HD_ / 128), 256, 0, stream>>>(
        xj, nullptr, degs, dists, dkt, skt, Wk_bf, nullptr, kbuf, B_ * N_, HD_, KKV);
    // V
    k_gemm<1, 1><<<(B_ * N_ / 128) * (HD_ / 128), 256, 0, stream>>>(
        xj, nullptr, degs, dists, dvt, svt, Wv_bf, nullptr, vbuf, B_ * N_, HD_, KKV);

    k_attn<<<B_, 256, 0, stream>>>(q, kbuf, vbuf, mask, flag, alpha, attn_bf);

    // attnO = attn @ W_o^T  (M=4096, N=512, K=512), out f32
    k_gemm<0, 0><<<(B_ / 128) * (DX_ / 128), 256, 0, stream>>>(
        nullptr, attn_bf, nullptr, nullptr, nullptr, nullptr, Wo_bf, attnO, nullptr, B_, DX_, HD_);

    k_ln<<<B_, 64, 0, stream>>>(xi, attnO, ln_g, ln_b, y);
}